// Round 12
// baseline (75.273 us; speedup 1.0000x reference)
//
#include <hip/hip_runtime.h>
#include <hip/hip_bf16.h>
#include <cstdint>
#include <cstddef>

#define NEG_ATT 0.2f
#define NEG_OUT 0.01f

constexpr int Bc = 8, Sc = 16, Nn = 256, Fd = 128, Cd = 128;
constexpr int NB = Sc * Nn;        // 4096 bend nodes per batch
constexpr int EB = NB * 16;        // 65536 bend edges
constexpr int ES = Nn * 16;        // 4096 section edges
constexpr int NROWS = Bc * NB;     // 32768 total rows
constexpr int CAP = 80;            // ELL capacity (true max deg ~45)

// ---- workspace layout (bytes) ----
constexpr size_t OFF_CONSTS = 0;                                   // 4 KB f32 consts
constexpr size_t OFF_WTB  = 4096;                                  // Wb^T bf16 [128][128]
constexpr size_t OFF_WTS  = OFF_WTB + (size_t)Fd * Cd * 2;
constexpr size_t OFF_HBP  = OFF_WTS + (size_t)Fd * Cd * 2;         // h_bend packed u32 [32768][64]
constexpr size_t OFF_HSP  = OFF_HBP + (size_t)NROWS * 64 * 4;      // h_sec packed
constexpr size_t OFF_SSB  = OFF_HSP + (size_t)NROWS * 64 * 4;      // s_src bend [32768]
constexpr size_t OFF_SDB  = OFF_SSB + (size_t)NROWS * 4;
constexpr size_t OFF_SSS  = OFF_SDB + (size_t)NROWS * 4;
constexpr size_t OFF_SDS  = OFF_SSS + (size_t)NROWS * 4;
constexpr size_t OFF_AEB  = OFF_SDS + (size_t)NROWS * 4;           // alpha_edge bend [B][EB]
constexpr size_t OFF_AES  = OFF_AEB + (size_t)Bc * EB * 4;         // alpha_edge sec [B][ES]
constexpr size_t OFF_ELLB = OFF_AES + (size_t)Bc * ES * 4;         // ELL bend [NB][CAP] u32
constexpr size_t OFF_ELLS = OFF_ELLB + (size_t)NB * CAP * 4;       // ELL sec  [Nn][CAP] u32
constexpr size_t OFF_FILB = OFF_ELLS + (size_t)Nn * CAP * 4;       // fill bend [NB] (zeroed)
constexpr size_t OFF_FILS = OFF_FILB + (size_t)NB * 4;             // fill sec [Nn]
constexpr int ZERO_U32 = NB + Nn;                                  // 4352 u32 to zero

// consts float layout: [0]=w0 [1]=w1 [2..5]=we_ae_b [6..9]=we_ae_s [16..527]=wa vectors
// [544..563] = staged enc_W(16)+enc_b(4)

typedef short bf16x8 __attribute__((ext_vector_type(8)));
typedef float f32x4 __attribute__((ext_vector_type(4)));
#if defined(__has_builtin)
#if __has_builtin(__builtin_amdgcn_fdot2_f32_bf16)
#define HAS_DOT2BF 1
typedef __bf16 bf16x2 __attribute__((ext_vector_type(2)));
#endif
#endif

__device__ inline unsigned short f2bf(float f) {
  unsigned int u = __float_as_uint(f);
  u += 0x7fffu + ((u >> 16) & 1u);
  return (unsigned short)(u >> 16);
}
__device__ inline float lrelu(float x, float s) { return x > 0.f ? x : x * s; }
__device__ inline float bflo(unsigned int u) { return __uint_as_float(u << 16); }
__device__ inline float bfhi(unsigned int u) { return __uint_as_float(u & 0xffff0000u); }
__device__ inline float wave_dot128(const float* Wrow, const float* a, int lane) {
  float2 wv = *(const float2*)(Wrow + 2 * lane);
  float2 av = *(const float2*)(a + 2 * lane);
  float p = wv.x * av.x + wv.y * av.y;
  for (int off = 32; off; off >>= 1) p += __shfl_xor(p, off);
  return p;
}
// one edge's contribution; slot = (byteoff, cpk_lo, cpk_hi, f32 c)
__device__ inline void edge_fma(unsigned int u, uint4 v, float& o0, float& o1) {
#ifdef HAS_DOT2BF
  o0 = __builtin_amdgcn_fdot2_f32_bf16(__builtin_bit_cast(bf16x2, u),
                                       __builtin_bit_cast(bf16x2, v.y), o0, false);
  o1 = __builtin_amdgcn_fdot2_f32_bf16(__builtin_bit_cast(bf16x2, u),
                                       __builtin_bit_cast(bf16x2, v.z), o1, false);
#else
  float c = __uint_as_float(v.w);
  o0 += c * bflo(u); o1 += c * bfhi(u);
#endif
}

// ---- setup: convw + wa dots + we_ae dots + fuse + stage enc + zero fill counters ----
__global__ __launch_bounds__(256) void k_setup(
    const float* Wb, const float* a_src_b, const float* a_dst_b,
    const float* Ws, const float* a_src_s, const float* a_dst_s,
    const float* We_b, const float* a_edge_b,
    const float* We_s, const float* a_edge_s,
    const float* fuse_w, const float* enc_W, const float* enc_b,
    float* consts, unsigned short* wtb, unsigned short* wts, unsigned int* fill_region) {
  int blk = blockIdx.x, t = threadIdx.x;
  if (blk < 128) {                                   // W -> bf16 transposed [col][k]
    int tid = blk * 256 + t;
    int which = tid >> 14, idx = tid & 16383;
    int c = idx >> 7, k = idx & 127;
    const float* W = which ? Ws : Wb;
    unsigned short* o = which ? wts : wtb;
    o[c * 128 + k] = f2bf(W[k * 128 + c]);
  } else if (blk < 160) {                            // wa dots: 512 length-128 dots
    int wave = t >> 6, lane = t & 63;
    int gw = (blk - 128) * 4 + wave;                 // 0..127
    int base = gw * 4;
    int v = base >> 7;
    const float* W = (v < 2) ? Wb : Ws;
    const float* a = (v == 0) ? a_src_b : (v == 1) ? a_dst_b : (v == 2) ? a_src_s : a_dst_s;
#pragma unroll
    for (int k = 0; k < 4; ++k) {
      int idx = base + k, f = idx & 127;
      float p = wave_dot128(W + f * 128, a, lane);
      if (lane == 0) consts[16 + v * 128 + f] = p;
    }
  } else if (blk == 160) {                           // we·a_edge dots + fuse softmax
    int wave = t >> 6, lane = t & 63;
    float pb = wave_dot128(We_b + wave * 128, a_edge_b, lane);
    float ps = wave_dot128(We_s + wave * 128, a_edge_s, lane);
    if (lane == 0) { consts[2 + wave] = pb; consts[6 + wave] = ps; }
    if (t == 0) {
      float f0 = fuse_w[0], f1 = fuse_w[1];
      float m = fmaxf(f0, f1);
      float e0 = __expf(f0 - m), e1 = __expf(f1 - m);
      consts[0] = e0 / (e0 + e1);
      consts[1] = e1 / (e0 + e1);
    }
  } else if (blk == 161) {                           // stage enc_W/enc_b
    if (t < 16) consts[544 + t] = enc_W[t];
    else if (t < 20) consts[544 + t] = enc_b[t - 16];
  } else {                                           // zero fill counters
    int zid = (blk - 162) * 256 + t;
    for (int z = zid; z < ZERO_U32; z += 2 * 256) fill_region[z] = 0;
  }
}

// ---- work: {gemm from f32 x + attention dots} | {edge encode} | {ELL scatter} ----
constexpr int GEMM_BLKS = NROWS / 64;                      // 512
constexpr int ENC_BLKS  = (Bc * (EB + ES)) / 256;          // 2176
constexpr int SCAT_BLKS = (EB + ES + 255) / 256;           // 272

__global__ __launch_bounds__(256) void k_work(
    const float* x, const float* consts,
    const unsigned short* wtb, const unsigned short* wts,
    unsigned int* hbp, unsigned int* hsp,
    float* ssb, float* sdb, float* sss, float* sds,
    const float* battr, const float* sattr, float* aeb, float* aes,
    const int* bsrc, const int* bdst, const int* ssrcA, const int* sdst,
    int* filb, int* fils, unsigned int* ellb, unsigned int* ells) {
  int blk = blockIdx.x, t = threadIdx.x;
  if (blk < GEMM_BLKS) {
    // ---- h = x @ {Wb,Ws} (f32 x loaded directly, bf16 MFMA) + 4 attention dots ----
    int wave = t >> 6, lane = t & 63;
    int m0 = blk * 64 + wave * 16;
    int r = lane & 15, kg = lane >> 4;
    f32x4 accB[8], accS[8];
#pragma unroll
    for (int i = 0; i < 8; ++i) { accB[i] = (f32x4){0,0,0,0}; accS[i] = (f32x4){0,0,0,0}; }
    float p0 = 0.f, p1 = 0.f, p2 = 0.f, p3 = 0.f;
    const float* wa = consts + 16;
#pragma unroll
    for (int ks = 0; ks < 4; ++ks) {
      int wo = ks * 32 + kg * 8;
      const float* xrow = x + (size_t)(m0 + r) * 128 + wo;
      float4 xa = *(const float4*)xrow;
      float4 xc = *(const float4*)(xrow + 4);
      float4 w0a = *(const float4*)(wa + 0 * 128 + wo), w0b = *(const float4*)(wa + 0 * 128 + wo + 4);
      float4 w1a = *(const float4*)(wa + 1 * 128 + wo), w1b = *(const float4*)(wa + 1 * 128 + wo + 4);
      float4 w2a = *(const float4*)(wa + 2 * 128 + wo), w2b = *(const float4*)(wa + 2 * 128 + wo + 4);
      float4 w3a = *(const float4*)(wa + 3 * 128 + wo), w3b = *(const float4*)(wa + 3 * 128 + wo + 4);
      p0 += xa.x*w0a.x + xa.y*w0a.y + xa.z*w0a.z + xa.w*w0a.w
          + xc.x*w0b.x + xc.y*w0b.y + xc.z*w0b.z + xc.w*w0b.w;
      p1 += xa.x*w1a.x + xa.y*w1a.y + xa.z*w1a.z + xa.w*w1a.w
          + xc.x*w1b.x + xc.y*w1b.y + xc.z*w1b.z + xc.w*w1b.w;
      p2 += xa.x*w2a.x + xa.y*w2a.y + xa.z*w2a.z + xa.w*w2a.w
          + xc.x*w2b.x + xc.y*w2b.y + xc.z*w2b.z + xc.w*w2b.w;
      p3 += xa.x*w3a.x + xa.y*w3a.y + xa.z*w3a.z + xa.w*w3a.w
          + xc.x*w3b.x + xc.y*w3b.y + xc.z*w3b.z + xc.w*w3b.w;
      bf16x8 a;
      a[0] = (short)f2bf(xa.x); a[1] = (short)f2bf(xa.y);
      a[2] = (short)f2bf(xa.z); a[3] = (short)f2bf(xa.w);
      a[4] = (short)f2bf(xc.x); a[5] = (short)f2bf(xc.y);
      a[6] = (short)f2bf(xc.z); a[7] = (short)f2bf(xc.w);
#pragma unroll
      for (int cb = 0; cb < 8; ++cb) {
        bf16x8 bb = *(const bf16x8*)(wtb + (size_t)(cb * 16 + r) * 128 + wo);
        accB[cb] = __builtin_amdgcn_mfma_f32_16x16x32_bf16(a, bb, accB[cb], 0, 0, 0);
        bf16x8 bs = *(const bf16x8*)(wts + (size_t)(cb * 16 + r) * 128 + wo);
        accS[cb] = __builtin_amdgcn_mfma_f32_16x16x32_bf16(a, bs, accS[cb], 0, 0, 0);
      }
    }
    // reduce dots across kg groups (lanes r, r+16, r+32, r+48)
    p0 += __shfl_xor(p0, 16); p0 += __shfl_xor(p0, 32);
    p1 += __shfl_xor(p1, 16); p1 += __shfl_xor(p1, 32);
    p2 += __shfl_xor(p2, 16); p2 += __shfl_xor(p2, 32);
    p3 += __shfl_xor(p3, 16); p3 += __shfl_xor(p3, 32);
    if (lane < 16) {
      int row = m0 + lane;
      ssb[row] = p0; sdb[row] = p1; sss[row] = p2; sds[row] = p3;
    }
#pragma unroll
    for (int cb = 0; cb < 4; ++cb)
#pragma unroll
      for (int i = 0; i < 4; ++i) {
        size_t idx = (size_t)(m0 + kg * 4 + i) * 64 + cb * 16 + r;
        hbp[idx] = (unsigned int)f2bf(accB[cb][i]) | ((unsigned int)f2bf(accB[cb + 4][i]) << 16);
        hsp[idx] = (unsigned int)f2bf(accS[cb][i]) | ((unsigned int)f2bf(accS[cb + 4][i]) << 16);
      }
  } else if (blk < GEMM_BLKS + ENC_BLKS) {
    // ---- edge encode -> alpha_e ----
    int idx = (blk - GEMM_BLKS) * 256 + t;
    const float* encW = consts + 544;
    bool isB = idx < Bc * EB;
    const float* attr = isB ? battr : sattr;
    const float* wae = consts + (isB ? 2 : 6);
    float* dst = isB ? aeb : aes;
    int id2 = isB ? idx : idx - Bc * EB;
    float4 at = *(const float4*)(attr + (size_t)id2 * 4);
    float e0 = encW[16] + at.x * encW[0] + at.y * encW[4] + at.z * encW[8]  + at.w * encW[12];
    float e1 = encW[17] + at.x * encW[1] + at.y * encW[5] + at.z * encW[9]  + at.w * encW[13];
    float e2 = encW[18] + at.x * encW[2] + at.y * encW[6] + at.z * encW[10] + at.w * encW[14];
    float e3 = encW[19] + at.x * encW[3] + at.y * encW[7] + at.z * encW[11] + at.w * encW[15];
    dst[id2] = e0 * wae[0] + e1 * wae[1] + e2 * wae[2] + e3 * wae[3];
  } else {
    // ---- ELL scatter (src<<16 | edge); fill counters zeroed by k_setup ----
    int tid = (blk - GEMM_BLKS - ENC_BLKS) * 256 + t;
    if (tid < EB) {
      int d = bdst[tid];
      int slot = atomicAdd(&filb[d], 1);
      if (slot < CAP) ellb[(size_t)d * CAP + slot] = ((unsigned int)bsrc[tid] << 16) | (unsigned int)tid;
    } else if (tid < EB + ES) {
      int e = tid - EB;
      int d = sdst[e];
      int slot = atomicAdd(&fils[d], 1);
      if (slot < CAP) ells[(size_t)d * CAP + slot] = ((unsigned int)ssrcA[e] << 16) | (unsigned int)e;
    }
  }
}

// ---- fused gather, phase-split: wave = (node, phase); combine via LDS ----
__global__ __launch_bounds__(256) void k_gather(
    const float* ssb, const float* sdb, const float* aeb,
    const int* filb, const unsigned int* ellb, const unsigned int* hbp, const float* bias_b,
    const float* sss, const float* sds, const float* aes,
    const int* fils, const unsigned int* ells, const unsigned int* hsp, const float* bias_s,
    const float* consts, float* out) {
  __shared__ uint4 slots[4][64];     // per-wave edge slots
  __shared__ float cmb[2][128];      // section partials per node
  int wg = blockIdx.x;
  int w = threadIdx.x >> 6, lane = threadIdx.x & 63;
  int b = wg & 7;
  int nl = w >> 1, ph = w & 1;       // node-local 0/1, phase 0=bend 1=sec
  int i = ((wg >> 3) << 1) + nl;     // node in batch [0,4096)
  int wid = (b << 12) + i;
  int il = i & 255;
  int rowBase = wid - il;

  float o0 = 0.f, o1 = 0.f;

  const float* ssrc; const float* aeArr; const unsigned int* hB; const unsigned int* ellR;
  int deg; float sd, ssSelf; int selfIdx;
  if (ph == 0) {
    deg = filb[i];  if (deg > CAP) deg = CAP;
    ssrc = ssb + ((size_t)b << 12);
    aeArr = aeb + (size_t)b * EB;
    hB = hbp + (((size_t)b << 12) << 6);
    ellR = ellb + (size_t)i * CAP;
    sd = sdb[wid]; selfIdx = i;
  } else {
    deg = fils[il]; if (deg > CAP) deg = CAP;
    ssrc = sss + rowBase;
    aeArr = aes + (size_t)b * ES;
    hB = hsp + ((size_t)rowBase << 6);
    ellR = ells + (size_t)il * CAP;
    sd = sds[wid]; selfIdx = il;
  }
  ssSelf = ssrc[selfIdx];
  unsigned int uSelf = (ph == 0 ? hbp : hsp)[((size_t)wid << 6) + lane];
  uint4* sl = slots[w];

  if (deg <= 64) {
    bool v = lane < deg;
    unsigned int ev = v ? ellR[lane] : 0u;
    int s = ev >> 16;
    int e = ev & 0xffffu;
    float aev = v ? aeArr[e] : 0.f;
    float xs = ssrc[s];

    // exp without max-subtraction: |scores| <~ 15, f32 exp safe
    float c = v ? __expf(lrelu(xs + sd + aev, NEG_ATT)) : 0.f;
    float asum = aev, se = c;
    for (int off = 32; off; off >>= 1) {
      asum += __shfl_xor(asum, off);
      se += __shfl_xor(se, off);
    }
    float aS = lrelu(ssSelf + sd + asum / (float)(deg > 0 ? deg : 1), NEG_ATT);
    float eS = __expf(aS);
    float inv = 1.f / (se + eS);
    float cn = c * inv;
    {
      unsigned int c16 = (unsigned int)f2bf(cn);
      uint4 slot;
      slot.x = (unsigned int)s << 8; slot.y = c16; slot.z = c16 << 16; slot.w = __float_as_uint(cn);
      sl[lane] = slot;
    }
    const char* hc = (const char*)hB;
    int lb4 = lane * 4;
    int j = 0;
    for (; j + 4 <= deg; j += 4) {
      uint4 v0 = sl[j], v1 = sl[j+1], v2 = sl[j+2], v3 = sl[j+3];
      unsigned int u0 = *(const unsigned int*)(hc + v0.x + lb4);
      unsigned int u1 = *(const unsigned int*)(hc + v1.x + lb4);
      unsigned int u2 = *(const unsigned int*)(hc + v2.x + lb4);
      unsigned int u3 = *(const unsigned int*)(hc + v3.x + lb4);
      edge_fma(u0, v0, o0, o1); edge_fma(u1, v1, o0, o1);
      edge_fma(u2, v2, o0, o1); edge_fma(u3, v3, o0, o1);
    }
    for (; j < deg; ++j) {
      uint4 vv = sl[j];
      unsigned int u = *(const unsigned int*)(hc + vv.x + lb4);
      edge_fma(u, vv, o0, o1);
    }
    float cSelf = eS * inv;
    o0 += cSelf * bflo(uSelf); o1 += cSelf * bfhi(uSelf);
  } else {
    // ---- cold fallback (64 < deg <= CAP): 3-pass with max, serial accumulate ----
    float asum = 0.f;
    for (int p = lane; p < deg; p += 64) asum += aeArr[ellR[p] & 0xffffu];
    for (int off = 32; off; off >>= 1) asum += __shfl_xor(asum, off);
    float aS = lrelu(ssSelf + sd + asum / (float)(deg > 0 ? deg : 1), NEG_ATT);
    float m = aS;
    for (int p = lane; p < deg; p += 64) {
      unsigned int v = ellR[p];
      m = fmaxf(m, lrelu(ssrc[v >> 16] + sd + aeArr[v & 0xffffu], NEG_ATT));
    }
    for (int off = 32; off; off >>= 1) m = fmaxf(m, __shfl_xor(m, off));
    float se = 0.f;
    for (int p = lane; p < deg; p += 64) {
      unsigned int v = ellR[p];
      se += __expf(lrelu(ssrc[v >> 16] + sd + aeArr[v & 0xffffu], NEG_ATT) - m);
    }
    for (int off = 32; off; off >>= 1) se += __shfl_xor(se, off);
    se += __expf(aS - m);
    float inv = 1.f / se;
    for (int j = 0; j < deg; ++j) {
      unsigned int v = ellR[j];
      int s = v >> 16;
      float c = __expf(lrelu(ssrc[s] + sd + aeArr[v & 0xffffu], NEG_ATT) - m) * inv;
      unsigned int u = (hB + ((size_t)s << 6))[lane];
      o0 += c * bflo(u); o1 += c * bfhi(u);
    }
    float cSelf = __expf(aS - m) * inv;
    o0 += cSelf * bflo(uSelf); o1 += cSelf * bfhi(uSelf);
  }

  // ---- combine: sec waves publish, bend waves fuse + write ----
  if (ph == 1) { cmb[nl][lane] = o0; cmb[nl][64 + lane] = o1; }
  __syncthreads();
  if (ph == 0) {
    float w0 = consts[0], w1 = consts[1];
    size_t o = (size_t)wid << 7;
    out[o + lane]      = w0 * lrelu(o0 + bias_b[lane], NEG_OUT)
                       + w1 * (cmb[nl][lane] + bias_s[lane]);
    out[o + 64 + lane] = w0 * lrelu(o1 + bias_b[lane + 64], NEG_OUT)
                       + w1 * (cmb[nl][64 + lane] + bias_s[lane + 64]);
  }
}

extern "C" void kernel_launch(void* const* d_in, const int* in_sizes, int n_in,
                              void* d_out, int out_size, void* d_ws, size_t ws_size,
                              hipStream_t stream) {
  (void)in_sizes; (void)n_in; (void)out_size; (void)ws_size;
  const float* x        = (const float*)d_in[0];
  const int*   sec_ei   = (const int*)d_in[1];
  const int*   bend_ei  = (const int*)d_in[2];
  const float* sec_attr = (const float*)d_in[3];
  const float* bend_attr= (const float*)d_in[4];
  const float* enc_W    = (const float*)d_in[5];
  const float* enc_b    = (const float*)d_in[6];
  const float* Wb       = (const float*)d_in[7];
  const float* a_src_b  = (const float*)d_in[8];
  const float* a_dst_b  = (const float*)d_in[9];
  const float* We_b     = (const float*)d_in[10];
  const float* a_edge_b = (const float*)d_in[11];
  const float* bias_b   = (const float*)d_in[12];
  const float* Ws       = (const float*)d_in[13];
  const float* a_src_s  = (const float*)d_in[14];
  const float* a_dst_s  = (const float*)d_in[15];
  const float* We_s     = (const float*)d_in[16];
  const float* a_edge_s = (const float*)d_in[17];
  const float* bias_s   = (const float*)d_in[18];
  const float* fuse_w   = (const float*)d_in[19];
  float* out = (float*)d_out;

  char* ws = (char*)d_ws;
  float* consts = (float*)(ws + OFF_CONSTS);
  unsigned short* wtb = (unsigned short*)(ws + OFF_WTB);
  unsigned short* wts = (unsigned short*)(ws + OFF_WTS);
  unsigned int* hbp = (unsigned int*)(ws + OFF_HBP);
  unsigned int* hsp = (unsigned int*)(ws + OFF_HSP);
  float* ssb = (float*)(ws + OFF_SSB);
  float* sdb = (float*)(ws + OFF_SDB);
  float* sss = (float*)(ws + OFF_SSS);
  float* sds = (float*)(ws + OFF_SDS);
  float* aeb = (float*)(ws + OFF_AEB);
  float* aes = (float*)(ws + OFF_AES);
  unsigned int* ellb = (unsigned int*)(ws + OFF_ELLB);
  unsigned int* ells = (unsigned int*)(ws + OFF_ELLS);
  int* filb = (int*)(ws + OFF_FILB);
  int* fils = (int*)(ws + OFF_FILS);
  unsigned int* fill_region = (unsigned int*)(ws + OFF_FILB);

  const int* bend_src = bend_ei;
  const int* bend_dst = bend_ei + EB;
  const int* sec_src  = sec_ei;
  const int* sec_dst  = sec_ei + ES;

  k_setup<<<164, 256, 0, stream>>>(Wb, a_src_b, a_dst_b, Ws, a_src_s, a_dst_s,
                                   We_b, a_edge_b, We_s, a_edge_s, fuse_w,
                                   enc_W, enc_b, consts, wtb, wts, fill_region);

  k_work<<<GEMM_BLKS + ENC_BLKS + SCAT_BLKS, 256, 0, stream>>>(
      x, consts, wtb, wts, hbp, hsp, ssb, sdb, sss, sds,
      bend_attr, sec_attr, aeb, aes,
      bend_src, bend_dst, sec_src, sec_dst,
      filb, fils, ellb, ells);

  k_gather<<<NROWS / 2, 256, 0, stream>>>(ssb, sdb, aeb, filb, ellb, hbp, bias_b,
                                          sss, sds, aes, fils, ells, hsp, bias_s,
                                          consts, out);
}

// Round 13
// 69.936 us; speedup vs baseline: 1.0763x; 1.0763x over previous
//
#include <hip/hip_runtime.h>
#include <hip/hip_bf16.h>
#include <cstdint>
#include <cstddef>

#define NEG_ATT 0.2f
#define NEG_OUT 0.01f

constexpr int Bc = 8, Sc = 16, Nn = 256, Fd = 128, Cd = 128;
constexpr int NB = Sc * Nn;        // 4096 bend nodes per batch
constexpr int EB = NB * 16;        // 65536 bend edges
constexpr int ES = Nn * 16;        // 4096 section edges
constexpr int NROWS = Bc * NB;     // 32768 total rows
constexpr int CAP = 80;            // ELL capacity (true max deg ~45)

// ---- workspace layout (bytes) ----
constexpr size_t OFF_CONSTS = 0;                                   // 4 KB f32 consts
constexpr size_t OFF_WTB  = 4096;                                  // Wb^T bf16 [128][128]
constexpr size_t OFF_WTS  = OFF_WTB + (size_t)Fd * Cd * 2;
constexpr size_t OFF_HBP  = OFF_WTS + (size_t)Fd * Cd * 2;         // h_bend packed u32 [32768][64]
constexpr size_t OFF_HSP  = OFF_HBP + (size_t)NROWS * 64 * 4;      // h_sec packed
constexpr size_t OFF_SSB  = OFF_HSP + (size_t)NROWS * 64 * 4;      // s_src bend [32768]
constexpr size_t OFF_SDB  = OFF_SSB + (size_t)NROWS * 4;
constexpr size_t OFF_SSS  = OFF_SDB + (size_t)NROWS * 4;
constexpr size_t OFF_SDS  = OFF_SSS + (size_t)NROWS * 4;
constexpr size_t OFF_AEB  = OFF_SDS + (size_t)NROWS * 4;           // alpha_edge bend [B][EB]
constexpr size_t OFF_AES  = OFF_AEB + (size_t)Bc * EB * 4;         // alpha_edge sec [B][ES]
constexpr size_t OFF_ELLB = OFF_AES + (size_t)Bc * ES * 4;         // ELL bend [NB][CAP] u32
constexpr size_t OFF_ELLS = OFF_ELLB + (size_t)NB * CAP * 4;       // ELL sec  [Nn][CAP] u32
constexpr size_t OFF_FILB = OFF_ELLS + (size_t)Nn * CAP * 4;       // fill bend [NB] (zeroed)
constexpr size_t OFF_FILS = OFF_FILB + (size_t)NB * 4;             // fill sec [Nn]
constexpr int ZERO_U32 = NB + Nn;                                  // 4352 u32 to zero

// consts float layout: [0]=w0 [1]=w1 [2..5]=we_ae_b [6..9]=we_ae_s [16..527]=wa vectors
// [544..563] = staged enc_W(16)+enc_b(4)

typedef short bf16x8 __attribute__((ext_vector_type(8)));
typedef float f32x4 __attribute__((ext_vector_type(4)));
#if defined(__has_builtin)
#if __has_builtin(__builtin_amdgcn_fdot2_f32_bf16)
#define HAS_DOT2BF 1
typedef __bf16 bf16x2 __attribute__((ext_vector_type(2)));
#endif
#endif

__device__ inline unsigned short f2bf(float f) {
  unsigned int u = __float_as_uint(f);
  u += 0x7fffu + ((u >> 16) & 1u);
  return (unsigned short)(u >> 16);
}
__device__ inline float lrelu(float x, float s) { return x > 0.f ? x : x * s; }
__device__ inline float bflo(unsigned int u) { return __uint_as_float(u << 16); }
__device__ inline float bfhi(unsigned int u) { return __uint_as_float(u & 0xffff0000u); }
__device__ inline float wave_dot128(const float* Wrow, const float* a, int lane) {
  float2 wv = *(const float2*)(Wrow + 2 * lane);
  float2 av = *(const float2*)(a + 2 * lane);
  float p = wv.x * av.x + wv.y * av.y;
  for (int off = 32; off; off >>= 1) p += __shfl_xor(p, off);
  return p;
}
// one edge's contribution: o0 += c*lo(u), o1 += c*hi(u); slot = (off, cpk_lo, cpk_hi, f32 c)
__device__ inline void edge_fma(unsigned int u, uint4 v, float& o0, float& o1) {
#ifdef HAS_DOT2BF
  o0 = __builtin_amdgcn_fdot2_f32_bf16(__builtin_bit_cast(bf16x2, u),
                                       __builtin_bit_cast(bf16x2, v.y), o0, false);
  o1 = __builtin_amdgcn_fdot2_f32_bf16(__builtin_bit_cast(bf16x2, u),
                                       __builtin_bit_cast(bf16x2, v.z), o1, false);
#else
  float c = __uint_as_float(v.w);
  o0 += c * bflo(u); o1 += c * bfhi(u);
#endif
}

// ---- setup: convw + wa dots + we_ae dots + fuse + stage enc + zero fill counters ----
__global__ __launch_bounds__(256) void k_setup(
    const float* Wb, const float* a_src_b, const float* a_dst_b,
    const float* Ws, const float* a_src_s, const float* a_dst_s,
    const float* We_b, const float* a_edge_b,
    const float* We_s, const float* a_edge_s,
    const float* fuse_w, const float* enc_W, const float* enc_b,
    float* consts, unsigned short* wtb, unsigned short* wts, unsigned int* fill_region) {
  int blk = blockIdx.x, t = threadIdx.x;
  if (blk < 128) {                                   // W -> bf16 transposed [col][k]
    int tid = blk * 256 + t;
    int which = tid >> 14, idx = tid & 16383;
    int c = idx >> 7, k = idx & 127;
    const float* W = which ? Ws : Wb;
    unsigned short* o = which ? wts : wtb;
    o[c * 128 + k] = f2bf(W[k * 128 + c]);
  } else if (blk < 160) {                            // wa dots: 512 length-128 dots
    int wave = t >> 6, lane = t & 63;
    int gw = (blk - 128) * 4 + wave;                 // 0..127
    int base = gw * 4;
    int v = base >> 7;
    const float* W = (v < 2) ? Wb : Ws;
    const float* a = (v == 0) ? a_src_b : (v == 1) ? a_dst_b : (v == 2) ? a_src_s : a_dst_s;
#pragma unroll
    for (int k = 0; k < 4; ++k) {
      int idx = base + k, f = idx & 127;
      float p = wave_dot128(W + f * 128, a, lane);
      if (lane == 0) consts[16 + v * 128 + f] = p;
    }
  } else if (blk == 160) {                           // we·a_edge dots + fuse softmax
    int wave = t >> 6, lane = t & 63;
    float pb = wave_dot128(We_b + wave * 128, a_edge_b, lane);
    float ps = wave_dot128(We_s + wave * 128, a_edge_s, lane);
    if (lane == 0) { consts[2 + wave] = pb; consts[6 + wave] = ps; }
    if (t == 0) {
      float f0 = fuse_w[0], f1 = fuse_w[1];
      float m = fmaxf(f0, f1);
      float e0 = __expf(f0 - m), e1 = __expf(f1 - m);
      consts[0] = e0 / (e0 + e1);
      consts[1] = e1 / (e0 + e1);
    }
  } else if (blk == 161) {                           // stage enc_W/enc_b
    if (t < 16) consts[544 + t] = enc_W[t];
    else if (t < 20) consts[544 + t] = enc_b[t - 16];
  } else {                                           // zero fill counters
    int zid = (blk - 162) * 256 + t;
    for (int z = zid; z < ZERO_U32; z += 2 * 256) fill_region[z] = 0;
  }
}

// ---- work: {gemm from f32 x + attention dots} | {edge encode} | {ELL scatter} ----
constexpr int GEMM_BLKS = NROWS / 64;                      // 512
constexpr int ENC_BLKS  = (Bc * (EB + ES)) / 256;          // 2176
constexpr int SCAT_BLKS = (EB + ES + 255) / 256;           // 272

__global__ __launch_bounds__(256) void k_work(
    const float* x, const float* consts,
    const unsigned short* wtb, const unsigned short* wts,
    unsigned int* hbp, unsigned int* hsp,
    float* ssb, float* sdb, float* sss, float* sds,
    const float* battr, const float* sattr, float* aeb, float* aes,
    const int* bsrc, const int* bdst, const int* ssrcA, const int* sdst,
    int* filb, int* fils, unsigned int* ellb, unsigned int* ells) {
  int blk = blockIdx.x, t = threadIdx.x;
  if (blk < GEMM_BLKS) {
    // ---- h = x @ {Wb,Ws} (f32 x loaded directly, bf16 MFMA) + 4 attention dots ----
    int wave = t >> 6, lane = t & 63;
    int m0 = blk * 64 + wave * 16;
    int r = lane & 15, kg = lane >> 4;
    f32x4 accB[8], accS[8];
#pragma unroll
    for (int i = 0; i < 8; ++i) { accB[i] = (f32x4){0,0,0,0}; accS[i] = (f32x4){0,0,0,0}; }
    float p0 = 0.f, p1 = 0.f, p2 = 0.f, p3 = 0.f;
    const float* wa = consts + 16;
#pragma unroll
    for (int ks = 0; ks < 4; ++ks) {
      int wo = ks * 32 + kg * 8;
      const float* xrow = x + (size_t)(m0 + r) * 128 + wo;
      float4 xa = *(const float4*)xrow;
      float4 xc = *(const float4*)(xrow + 4);
      float4 w0a = *(const float4*)(wa + 0 * 128 + wo), w0b = *(const float4*)(wa + 0 * 128 + wo + 4);
      float4 w1a = *(const float4*)(wa + 1 * 128 + wo), w1b = *(const float4*)(wa + 1 * 128 + wo + 4);
      float4 w2a = *(const float4*)(wa + 2 * 128 + wo), w2b = *(const float4*)(wa + 2 * 128 + wo + 4);
      float4 w3a = *(const float4*)(wa + 3 * 128 + wo), w3b = *(const float4*)(wa + 3 * 128 + wo + 4);
      p0 += xa.x*w0a.x + xa.y*w0a.y + xa.z*w0a.z + xa.w*w0a.w
          + xc.x*w0b.x + xc.y*w0b.y + xc.z*w0b.z + xc.w*w0b.w;
      p1 += xa.x*w1a.x + xa.y*w1a.y + xa.z*w1a.z + xa.w*w1a.w
          + xc.x*w1b.x + xc.y*w1b.y + xc.z*w1b.z + xc.w*w1b.w;
      p2 += xa.x*w2a.x + xa.y*w2a.y + xa.z*w2a.z + xa.w*w2a.w
          + xc.x*w2b.x + xc.y*w2b.y + xc.z*w2b.z + xc.w*w2b.w;
      p3 += xa.x*w3a.x + xa.y*w3a.y + xa.z*w3a.z + xa.w*w3a.w
          + xc.x*w3b.x + xc.y*w3b.y + xc.z*w3b.z + xc.w*w3b.w;
      bf16x8 a;
      a[0] = (short)f2bf(xa.x); a[1] = (short)f2bf(xa.y);
      a[2] = (short)f2bf(xa.z); a[3] = (short)f2bf(xa.w);
      a[4] = (short)f2bf(xc.x); a[5] = (short)f2bf(xc.y);
      a[6] = (short)f2bf(xc.z); a[7] = (short)f2bf(xc.w);
#pragma unroll
      for (int cb = 0; cb < 8; ++cb) {
        bf16x8 bb = *(const bf16x8*)(wtb + (size_t)(cb * 16 + r) * 128 + wo);
        accB[cb] = __builtin_amdgcn_mfma_f32_16x16x32_bf16(a, bb, accB[cb], 0, 0, 0);
        bf16x8 bs = *(const bf16x8*)(wts + (size_t)(cb * 16 + r) * 128 + wo);
        accS[cb] = __builtin_amdgcn_mfma_f32_16x16x32_bf16(a, bs, accS[cb], 0, 0, 0);
      }
    }
    // reduce dots across kg groups (lanes r, r+16, r+32, r+48)
    p0 += __shfl_xor(p0, 16); p0 += __shfl_xor(p0, 32);
    p1 += __shfl_xor(p1, 16); p1 += __shfl_xor(p1, 32);
    p2 += __shfl_xor(p2, 16); p2 += __shfl_xor(p2, 32);
    p3 += __shfl_xor(p3, 16); p3 += __shfl_xor(p3, 32);
    if (lane < 16) {
      int row = m0 + lane;
      ssb[row] = p0; sdb[row] = p1; sss[row] = p2; sds[row] = p3;
    }
#pragma unroll
    for (int cb = 0; cb < 4; ++cb)
#pragma unroll
      for (int i = 0; i < 4; ++i) {
        size_t idx = (size_t)(m0 + kg * 4 + i) * 64 + cb * 16 + r;
        hbp[idx] = (unsigned int)f2bf(accB[cb][i]) | ((unsigned int)f2bf(accB[cb + 4][i]) << 16);
        hsp[idx] = (unsigned int)f2bf(accS[cb][i]) | ((unsigned int)f2bf(accS[cb + 4][i]) << 16);
      }
  } else if (blk < GEMM_BLKS + ENC_BLKS) {
    // ---- edge encode -> alpha_e ----
    int idx = (blk - GEMM_BLKS) * 256 + t;
    const float* encW = consts + 544;
    bool isB = idx < Bc * EB;
    const float* attr = isB ? battr : sattr;
    const float* wae = consts + (isB ? 2 : 6);
    float* dst = isB ? aeb : aes;
    int id2 = isB ? idx : idx - Bc * EB;
    float4 at = *(const float4*)(attr + (size_t)id2 * 4);
    float e0 = encW[16] + at.x * encW[0] + at.y * encW[4] + at.z * encW[8]  + at.w * encW[12];
    float e1 = encW[17] + at.x * encW[1] + at.y * encW[5] + at.z * encW[9]  + at.w * encW[13];
    float e2 = encW[18] + at.x * encW[2] + at.y * encW[6] + at.z * encW[10] + at.w * encW[14];
    float e3 = encW[19] + at.x * encW[3] + at.y * encW[7] + at.z * encW[11] + at.w * encW[15];
    dst[id2] = e0 * wae[0] + e1 * wae[1] + e2 * wae[2] + e3 * wae[3];
  } else {
    // ---- ELL scatter (src<<16 | edge); fill counters zeroed by k_setup ----
    int tid = (blk - GEMM_BLKS - ENC_BLKS) * 256 + t;
    if (tid < EB) {
      int d = bdst[tid];
      int slot = atomicAdd(&filb[d], 1);
      if (slot < CAP) ellb[(size_t)d * CAP + slot] = ((unsigned int)bsrc[tid] << 16) | (unsigned int)tid;
    } else if (tid < EB + ES) {
      int e = tid - EB;
      int d = sdst[e];
      int slot = atomicAdd(&fils[d], 1);
      if (slot < CAP) ells[(size_t)d * CAP + slot] = ((unsigned int)ssrcA[e] << 16) | (unsigned int)e;
    }
  }
}

// ---- fused gather: ELL softmax (no-max, exp-safe range) + dot2-bf16 accumulate ----
__global__ __launch_bounds__(256) void k_gather(
    const float* ssb, const float* sdb, const float* aeb,
    const int* filb, const unsigned int* ellb, const unsigned int* hbp, const float* bias_b,
    const float* sss, const float* sds, const float* aes,
    const int* fils, const unsigned int* ells, const unsigned int* hsp, const float* bias_s,
    const float* consts, float* out) {
  __shared__ uint4 lds[4][128];   // [wave][0..63]=bend slots, [64..127]=sec slots
  int wg = blockIdx.x;
  int wave = threadIdx.x >> 6, lane = threadIdx.x & 63;
  int b = wg & 7;
  int i = ((wg >> 3) << 2) + wave;        // node in batch [0,4096)
  int wid = (b << 12) + i;
  int il = i & 255;
  int rowBase = wid - il;

  float oB0 = 0.f, oB1 = 0.f, oS0 = 0.f, oS1 = 0.f;

  int degB = filb[i];  if (degB > CAP) degB = CAP;
  int degS = fils[il]; if (degS > CAP) degS = CAP;
  const float* ssrcBb = ssb + ((size_t)b << 12);
  const float* ssrcGs = sss + rowBase;
  const float* aeBb = aeb + (size_t)b * EB;
  const float* aeBs = aes + (size_t)b * ES;
  const unsigned int* hBb = hbp + (((size_t)b << 12) << 6);
  const unsigned int* hGs = hsp + ((size_t)rowBase << 6);
  const unsigned int* ellBr = ellb + (size_t)i * CAP;
  const unsigned int* ellSr = ells + (size_t)il * CAP;
  unsigned int uSelfB = hbp[((size_t)wid << 6) + lane];
  unsigned int uSelfS = hsp[((size_t)wid << 6) + lane];
  float sdB = sdb[wid], sdS = sds[wid];
  float ssSelfB = ssrcBb[i], ssSelfS = ssrcGs[il];

  uint4* ldsw = lds[wave];

  if (degB <= 64 && degS <= 64) {
    bool vB = lane < degB, vS = lane < degS;
    unsigned int evB = vB ? ellBr[lane] : 0u;
    unsigned int evS = vS ? ellSr[lane] : 0u;
    int sB = evB >> 16, sS = evS >> 16;
    int eB = evB & 0xffffu, eS = evS & 0xffffu;
    float aevB = vB ? aeBb[eB] : 0.f;
    float aevS = vS ? aeBs[eS] : 0.f;
    float xsB = ssrcBb[sB];
    float xsS = ssrcGs[sS];

    // exp without max-subtraction: scores |a| <~ 15, f32 exp safe to ~88
    float cB = vB ? __expf(lrelu(xsB + sdB + aevB, NEG_ATT)) : 0.f;
    float cS2 = vS ? __expf(lrelu(xsS + sdS + aevS, NEG_ATT)) : 0.f;

    float asumB = aevB, asumS = aevS, seB = cB, seS = cS2;
    for (int off = 32; off; off >>= 1) {
      asumB += __shfl_xor(asumB, off);
      asumS += __shfl_xor(asumS, off);
      seB += __shfl_xor(seB, off);
      seS += __shfl_xor(seS, off);
    }
    float aSB = lrelu(ssSelfB + sdB + asumB / (float)(degB > 0 ? degB : 1), NEG_ATT);
    float aSS = lrelu(ssSelfS + sdS + asumS / (float)(degS > 0 ? degS : 1), NEG_ATT);
    float eSB = __expf(aSB), eSS = __expf(aSS);
    float invB = 1.f / (seB + eSB);
    float invS = 1.f / (seS + eSS);

    // publish slots: (byteoff, cpk_lo, cpk_hi, f32 c)
    {
      float cnB = cB * invB, cnS = cS2 * invS;
      unsigned int cb16 = (unsigned int)f2bf(cnB);
      unsigned int cs16 = (unsigned int)f2bf(cnS);
      uint4 slotB, slotS;
      slotB.x = (unsigned int)sB << 8; slotB.y = cb16; slotB.z = cb16 << 16; slotB.w = __float_as_uint(cnB);
      slotS.x = (unsigned int)sS << 8; slotS.y = cs16; slotS.z = cs16 << 16; slotS.w = __float_as_uint(cnS);
      ldsw[lane] = slotB;
      ldsw[64 + lane] = slotS;
    }

    const char* hBc = (const char*)hBb;
    const char* hGc = (const char*)hGs;
    int lb4 = lane * 4;
    int j = 0;
    for (; j + 4 <= degB; j += 4) {
      uint4 v0 = ldsw[j], v1 = ldsw[j+1], v2 = ldsw[j+2], v3 = ldsw[j+3];
      unsigned int u0 = *(const unsigned int*)(hBc + v0.x + lb4);
      unsigned int u1 = *(const unsigned int*)(hBc + v1.x + lb4);
      unsigned int u2 = *(const unsigned int*)(hBc + v2.x + lb4);
      unsigned int u3 = *(const unsigned int*)(hBc + v3.x + lb4);
      edge_fma(u0, v0, oB0, oB1); edge_fma(u1, v1, oB0, oB1);
      edge_fma(u2, v2, oB0, oB1); edge_fma(u3, v3, oB0, oB1);
    }
    for (; j < degB; ++j) {
      uint4 v = ldsw[j];
      unsigned int u = *(const unsigned int*)(hBc + v.x + lb4);
      edge_fma(u, v, oB0, oB1);
    }
    j = 0;
    for (; j + 4 <= degS; j += 4) {
      uint4 v0 = ldsw[64+j], v1 = ldsw[64+j+1], v2 = ldsw[64+j+2], v3 = ldsw[64+j+3];
      unsigned int u0 = *(const unsigned int*)(hGc + v0.x + lb4);
      unsigned int u1 = *(const unsigned int*)(hGc + v1.x + lb4);
      unsigned int u2 = *(const unsigned int*)(hGc + v2.x + lb4);
      unsigned int u3 = *(const unsigned int*)(hGc + v3.x + lb4);
      edge_fma(u0, v0, oS0, oS1); edge_fma(u1, v1, oS0, oS1);
      edge_fma(u2, v2, oS0, oS1); edge_fma(u3, v3, oS0, oS1);
    }
    for (; j < degS; ++j) {
      uint4 v = ldsw[64+j];
      unsigned int u = *(const unsigned int*)(hGc + v.x + lb4);
      edge_fma(u, v, oS0, oS1);
    }
    // self-loop terms
    float cSelfB = eSB * invB;
    oB0 += cSelfB * bflo(uSelfB); oB1 += cSelfB * bfhi(uSelfB);
    float cSelfS = eSS * invS;
    oS0 += cSelfS * bflo(uSelfS); oS1 += cSelfS * bfhi(uSelfS);
  } else {
    // ---- cold fallback (64 < deg <= CAP), strided 3-pass + serial accumulate ----
    float mB, invB, aSB, mS, invS, aSS;
    {
      float asum = 0.f;
      for (int p = lane; p < degB; p += 64) asum += aeBb[ellBr[p] & 0xffffu];
      for (int off = 32; off; off >>= 1) asum += __shfl_xor(asum, off);
      aSB = lrelu(ssSelfB + sdB + asum / (float)(degB > 0 ? degB : 1), NEG_ATT);
      mB = aSB;
      for (int p = lane; p < degB; p += 64) {
        unsigned int v = ellBr[p];
        mB = fmaxf(mB, lrelu(ssrcBb[v >> 16] + sdB + aeBb[v & 0xffffu], NEG_ATT));
      }
      for (int off = 32; off; off >>= 1) mB = fmaxf(mB, __shfl_xor(mB, off));
      float se = 0.f;
      for (int p = lane; p < degB; p += 64) {
        unsigned int v = ellBr[p];
        se += __expf(lrelu(ssrcBb[v >> 16] + sdB + aeBb[v & 0xffffu], NEG_ATT) - mB);
      }
      for (int off = 32; off; off >>= 1) se += __shfl_xor(se, off);
      se += __expf(aSB - mB);
      invB = 1.f / se;
      for (int j = 0; j < degB; ++j) {
        unsigned int v = ellBr[j];
        int s = v >> 16;
        float c = __expf(lrelu(ssrcBb[s] + sdB + aeBb[v & 0xffffu], NEG_ATT) - mB) * invB;
        unsigned int u = (hBb + ((size_t)s << 6))[lane];
        oB0 += c * bflo(u); oB1 += c * bfhi(u);
      }
      float cSelfB = __expf(aSB - mB) * invB;
      oB0 += cSelfB * bflo(uSelfB); oB1 += cSelfB * bfhi(uSelfB);
    }
    {
      float asum = 0.f;
      for (int p = lane; p < degS; p += 64) asum += aeBs[ellSr[p] & 0xffffu];
      for (int off = 32; off; off >>= 1) asum += __shfl_xor(asum, off);
      aSS = lrelu(ssSelfS + sdS + asum / (float)(degS > 0 ? degS : 1), NEG_ATT);
      mS = aSS;
      for (int p = lane; p < degS; p += 64) {
        unsigned int v = ellSr[p];
        mS = fmaxf(mS, lrelu(ssrcGs[v >> 16] + sdS + aeBs[v & 0xffffu], NEG_ATT));
      }
      for (int off = 32; off; off >>= 1) mS = fmaxf(mS, __shfl_xor(mS, off));
      float se = 0.f;
      for (int p = lane; p < degS; p += 64) {
        unsigned int v = ellSr[p];
        se += __expf(lrelu(ssrcGs[v >> 16] + sdS + aeBs[v & 0xffffu], NEG_ATT) - mS);
      }
      for (int off = 32; off; off >>= 1) se += __shfl_xor(se, off);
      se += __expf(aSS - mS);
      invS = 1.f / se;
      for (int j = 0; j < degS; ++j) {
        unsigned int v = ellSr[j];
        int s = v >> 16;
        float c = __expf(lrelu(ssrcGs[s] + sdS + aeBs[v & 0xffffu], NEG_ATT) - mS) * invS;
        unsigned int u = (hGs + ((size_t)s << 6))[lane];
        oS0 += c * bflo(u); oS1 += c * bfhi(u);
      }
      float cSelfS = __expf(aSS - mS) * invS;
      oS0 += cSelfS * bflo(uSelfS); oS1 += cSelfS * bfhi(uSelfS);
    }
  }

  float w0 = consts[0], w1 = consts[1];
  size_t o = (size_t)wid << 7;
  out[o + lane]      = w0 * lrelu(oB0 + bias_b[lane], NEG_OUT)      + w1 * (oS0 + bias_s[lane]);
  out[o + 64 + lane] = w0 * lrelu(oB1 + bias_b[lane + 64], NEG_OUT) + w1 * (oS1 + bias_s[lane + 64]);
}

extern "C" void kernel_launch(void* const* d_in, const int* in_sizes, int n_in,
                              void* d_out, int out_size, void* d_ws, size_t ws_size,
                              hipStream_t stream) {
  (void)in_sizes; (void)n_in; (void)out_size; (void)ws_size;
  const float* x        = (const float*)d_in[0];
  const int*   sec_ei   = (const int*)d_in[1];
  const int*   bend_ei  = (const int*)d_in[2];
  const float* sec_attr = (const float*)d_in[3];
  const float* bend_attr= (const float*)d_in[4];
  const float* enc_W    = (const float*)d_in[5];
  const float* enc_b    = (const float*)d_in[6];
  const float* Wb       = (const float*)d_in[7];
  const float* a_src_b  = (const float*)d_in[8];
  const float* a_dst_b  = (const float*)d_in[9];
  const float* We_b     = (const float*)d_in[10];
  const float* a_edge_b = (const float*)d_in[11];
  const float* bias_b   = (const float*)d_in[12];
  const float* Ws       = (const float*)d_in[13];
  const float* a_src_s  = (const float*)d_in[14];
  const float* a_dst_s  = (const float*)d_in[15];
  const float* We_s     = (const float*)d_in[16];
  const float* a_edge_s = (const float*)d_in[17];
  const float* bias_s   = (const float*)d_in[18];
  const float* fuse_w   = (const float*)d_in[19];
  float* out = (float*)d_out;

  char* ws = (char*)d_ws;
  float* consts = (float*)(ws + OFF_CONSTS);
  unsigned short* wtb = (unsigned short*)(ws + OFF_WTB);
  unsigned short* wts = (unsigned short*)(ws + OFF_WTS);
  unsigned int* hbp = (unsigned int*)(ws + OFF_HBP);
  unsigned int* hsp = (unsigned int*)(ws + OFF_HSP);
  float* ssb = (float*)(ws + OFF_SSB);
  float* sdb = (float*)(ws + OFF_SDB);
  float* sss = (float*)(ws + OFF_SSS);
  float* sds = (float*)(ws + OFF_SDS);
  float* aeb = (float*)(ws + OFF_AEB);
  float* aes = (float*)(ws + OFF_AES);
  unsigned int* ellb = (unsigned int*)(ws + OFF_ELLB);
  unsigned int* ells = (unsigned int*)(ws + OFF_ELLS);
  int* filb = (int*)(ws + OFF_FILB);
  int* fils = (int*)(ws + OFF_FILS);
  unsigned int* fill_region = (unsigned int*)(ws + OFF_FILB);

  const int* bend_src = bend_ei;
  const int* bend_dst = bend_ei + EB;
  const int* sec_src  = sec_ei;
  const int* sec_dst  = sec_ei + ES;

  k_setup<<<164, 256, 0, stream>>>(Wb, a_src_b, a_dst_b, Ws, a_src_s, a_dst_s,
                                   We_b, a_edge_b, We_s, a_edge_s, fuse_w,
                                   enc_W, enc_b, consts, wtb, wts, fill_region);

  k_work<<<GEMM_BLKS + ENC_BLKS + SCAT_BLKS, 256, 0, stream>>>(
      x, consts, wtb, wts, hbp, hsp, ssb, sdb, sss, sds,
      bend_attr, sec_attr, aeb, aes,
      bend_src, bend_dst, sec_src, sec_dst,
      filb, fils, ellb, ells);

  k_gather<<<NROWS / 4, 256, 0, stream>>>(ssb, sdb, aeb, filb, ellb, hbp, bias_b,
                                          sss, sds, aes, fils, ells, hsp, bias_s,
                                          consts, out);
}

// Round 14
// 68.412 us; speedup vs baseline: 1.1003x; 1.0223x over previous
//
#include <hip/hip_runtime.h>
#include <hip/hip_bf16.h>
#include <cstdint>
#include <cstddef>

#define NEG_ATT 0.2f
#define NEG_OUT 0.01f

constexpr int Bc = 8, Sc = 16, Nn = 256, Fd = 128, Cd = 128;
constexpr int NB = Sc * Nn;        // 4096 bend nodes per batch
constexpr int EB = NB * 16;        // 65536 bend edges
constexpr int ES = Nn * 16;        // 4096 section edges
constexpr int NROWS = Bc * NB;     // 32768 total rows
constexpr int CAP = 80;            // ELL capacity (true max deg ~45)

// ---- workspace layout (bytes) ----
constexpr size_t OFF_CONSTS = 0;                                   // 4 KB f32 consts
constexpr size_t OFF_WTB  = 4096;                                  // Wb^T bf16 [128][128]
constexpr size_t OFF_WTS  = OFF_WTB + (size_t)Fd * Cd * 2;
constexpr size_t OFF_HBP  = OFF_WTS + (size_t)Fd * Cd * 2;         // h_bend packed u32 [32768][64]
constexpr size_t OFF_HSP  = OFF_HBP + (size_t)NROWS * 64 * 4;      // h_sec packed
constexpr size_t OFF_SSB  = OFF_HSP + (size_t)NROWS * 64 * 4;      // s_src bend [32768]
constexpr size_t OFF_SDB  = OFF_SSB + (size_t)NROWS * 4;
constexpr size_t OFF_SSS  = OFF_SDB + (size_t)NROWS * 4;
constexpr size_t OFF_SDS  = OFF_SSS + (size_t)NROWS * 4;
constexpr size_t OFF_AEB  = OFF_SDS + (size_t)NROWS * 4;           // alpha_edge bend [B][EB]
constexpr size_t OFF_AES  = OFF_AEB + (size_t)Bc * EB * 4;         // alpha_edge sec [B][ES]
constexpr size_t OFF_ELLB = OFF_AES + (size_t)Bc * ES * 4;         // ELL bend [NB][CAP] u32
constexpr size_t OFF_ELLS = OFF_ELLB + (size_t)NB * CAP * 4;       // ELL sec  [Nn][CAP] u32
constexpr size_t OFF_FILB = OFF_ELLS + (size_t)Nn * CAP * 4;       // fill bend [NB] (zeroed)
constexpr size_t OFF_FILS = OFF_FILB + (size_t)NB * 4;             // fill sec [Nn]
constexpr int ZERO_U32 = NB + Nn;                                  // 4352 u32 to zero

// consts float layout: [0]=w0 [1]=w1 [2..5]=we_ae_b [6..9]=we_ae_s [16..527]=wa vectors
// [544..563] = staged enc_W(16)+enc_b(4)

typedef short bf16x8 __attribute__((ext_vector_type(8)));
typedef float f32x4 __attribute__((ext_vector_type(4)));
#if defined(__has_builtin)
#if __has_builtin(__builtin_amdgcn_fdot2_f32_bf16)
#define HAS_DOT2BF 1
typedef __bf16 bf16x2 __attribute__((ext_vector_type(2)));
#endif
#endif

__device__ inline unsigned short f2bf(float f) {
  unsigned int u = __float_as_uint(f);
  u += 0x7fffu + ((u >> 16) & 1u);
  return (unsigned short)(u >> 16);
}
__device__ inline float lrelu(float x, float s) { return x > 0.f ? x : x * s; }
__device__ inline float bflo(unsigned int u) { return __uint_as_float(u << 16); }
__device__ inline float bfhi(unsigned int u) { return __uint_as_float(u & 0xffff0000u); }
__device__ inline float wave_dot128(const float* Wrow, const float* a, int lane) {
  float2 wv = *(const float2*)(Wrow + 2 * lane);
  float2 av = *(const float2*)(a + 2 * lane);
  float p = wv.x * av.x + wv.y * av.y;
  for (int off = 32; off; off >>= 1) p += __shfl_xor(p, off);
  return p;
}
// one edge's contribution: o0 += c*lo(u), o1 += c*hi(u); slot = (off, cpk_lo, cpk_hi, f32 c)
__device__ inline void edge_fma(unsigned int u, uint4 v, float& o0, float& o1) {
#ifdef HAS_DOT2BF
  o0 = __builtin_amdgcn_fdot2_f32_bf16(__builtin_bit_cast(bf16x2, u),
                                       __builtin_bit_cast(bf16x2, v.y), o0, false);
  o1 = __builtin_amdgcn_fdot2_f32_bf16(__builtin_bit_cast(bf16x2, u),
                                       __builtin_bit_cast(bf16x2, v.z), o1, false);
#else
  float c = __uint_as_float(v.w);
  o0 += c * bflo(u); o1 += c * bfhi(u);
#endif
}

// ---- setup: convw + wa dots + we_ae dots + fuse + stage enc + zero fill counters ----
__global__ __launch_bounds__(256) void k_setup(
    const float* Wb, const float* a_src_b, const float* a_dst_b,
    const float* Ws, const float* a_src_s, const float* a_dst_s,
    const float* We_b, const float* a_edge_b,
    const float* We_s, const float* a_edge_s,
    const float* fuse_w, const float* enc_W, const float* enc_b,
    float* consts, unsigned short* wtb, unsigned short* wts, unsigned int* fill_region) {
  int blk = blockIdx.x, t = threadIdx.x;
  if (blk < 128) {                                   // W -> bf16 transposed [col][k]
    int tid = blk * 256 + t;
    int which = tid >> 14, idx = tid & 16383;
    int c = idx >> 7, k = idx & 127;
    const float* W = which ? Ws : Wb;
    unsigned short* o = which ? wts : wtb;
    o[c * 128 + k] = f2bf(W[k * 128 + c]);
  } else if (blk < 160) {                            // wa dots: 512 length-128 dots
    int wave = t >> 6, lane = t & 63;
    int gw = (blk - 128) * 4 + wave;                 // 0..127
    int base = gw * 4;
    int v = base >> 7;
    const float* W = (v < 2) ? Wb : Ws;
    const float* a = (v == 0) ? a_src_b : (v == 1) ? a_dst_b : (v == 2) ? a_src_s : a_dst_s;
#pragma unroll
    for (int k = 0; k < 4; ++k) {
      int idx = base + k, f = idx & 127;
      float p = wave_dot128(W + f * 128, a, lane);
      if (lane == 0) consts[16 + v * 128 + f] = p;
    }
  } else if (blk == 160) {                           // we·a_edge dots + fuse softmax
    int wave = t >> 6, lane = t & 63;
    float pb = wave_dot128(We_b + wave * 128, a_edge_b, lane);
    float ps = wave_dot128(We_s + wave * 128, a_edge_s, lane);
    if (lane == 0) { consts[2 + wave] = pb; consts[6 + wave] = ps; }
    if (t == 0) {
      float f0 = fuse_w[0], f1 = fuse_w[1];
      float m = fmaxf(f0, f1);
      float e0 = __expf(f0 - m), e1 = __expf(f1 - m);
      consts[0] = e0 / (e0 + e1);
      consts[1] = e1 / (e0 + e1);
    }
  } else if (blk == 161) {                           // stage enc_W/enc_b
    if (t < 16) consts[544 + t] = enc_W[t];
    else if (t < 20) consts[544 + t] = enc_b[t - 16];
  } else {                                           // zero fill counters
    int zid = (blk - 162) * 256 + t;
    for (int z = zid; z < ZERO_U32; z += 2 * 256) fill_region[z] = 0;
  }
}

// ---- work: {gemm from f32 x + attention dots} | {edge encode} | {ELL scatter} ----
constexpr int GEMM_BLKS = NROWS / 64;                      // 512
constexpr int ENC_BLKS  = (Bc * (EB + ES)) / 256;          // 2176
constexpr int SCAT_BLKS = (EB + ES + 255) / 256;           // 272

__global__ __launch_bounds__(256) void k_work(
    const float* x, const float* consts,
    const unsigned short* wtb, const unsigned short* wts,
    unsigned int* hbp, unsigned int* hsp,
    float* ssb, float* sdb, float* sss, float* sds,
    const float* battr, const float* sattr, float* aeb, float* aes,
    const int* bsrc, const int* bdst, const int* ssrcA, const int* sdst,
    int* filb, int* fils, unsigned int* ellb, unsigned int* ells) {
  int blk = blockIdx.x, t = threadIdx.x;
  if (blk < GEMM_BLKS) {
    // ---- h = x @ {Wb,Ws} + 4 attention dots ----
    // XCD-align: batch = blk&7 matches k_gather's b = wg&7 so each batch's h
    // slice is written and read on the same XCD's L2.
    int wave = t >> 6, lane = t & 63;
    int m0 = ((blk & 7) << 12) | ((blk >> 3) << 6) | (wave << 4);
    int r = lane & 15, kg = lane >> 4;
    f32x4 accB[8], accS[8];
#pragma unroll
    for (int i = 0; i < 8; ++i) { accB[i] = (f32x4){0,0,0,0}; accS[i] = (f32x4){0,0,0,0}; }
    float p0 = 0.f, p1 = 0.f, p2 = 0.f, p3 = 0.f;
    const float* wa = consts + 16;
#pragma unroll
    for (int ks = 0; ks < 4; ++ks) {
      int wo = ks * 32 + kg * 8;
      const float* xrow = x + (size_t)(m0 + r) * 128 + wo;
      float4 xa = *(const float4*)xrow;
      float4 xc = *(const float4*)(xrow + 4);
      float4 w0a = *(const float4*)(wa + 0 * 128 + wo), w0b = *(const float4*)(wa + 0 * 128 + wo + 4);
      float4 w1a = *(const float4*)(wa + 1 * 128 + wo), w1b = *(const float4*)(wa + 1 * 128 + wo + 4);
      float4 w2a = *(const float4*)(wa + 2 * 128 + wo), w2b = *(const float4*)(wa + 2 * 128 + wo + 4);
      float4 w3a = *(const float4*)(wa + 3 * 128 + wo), w3b = *(const float4*)(wa + 3 * 128 + wo + 4);
      p0 += xa.x*w0a.x + xa.y*w0a.y + xa.z*w0a.z + xa.w*w0a.w
          + xc.x*w0b.x + xc.y*w0b.y + xc.z*w0b.z + xc.w*w0b.w;
      p1 += xa.x*w1a.x + xa.y*w1a.y + xa.z*w1a.z + xa.w*w1a.w
          + xc.x*w1b.x + xc.y*w1b.y + xc.z*w1b.z + xc.w*w1b.w;
      p2 += xa.x*w2a.x + xa.y*w2a.y + xa.z*w2a.z + xa.w*w2a.w
          + xc.x*w2b.x + xc.y*w2b.y + xc.z*w2b.z + xc.w*w2b.w;
      p3 += xa.x*w3a.x + xa.y*w3a.y + xa.z*w3a.z + xa.w*w3a.w
          + xc.x*w3b.x + xc.y*w3b.y + xc.z*w3b.z + xc.w*w3b.w;
      bf16x8 a;
      a[0] = (short)f2bf(xa.x); a[1] = (short)f2bf(xa.y);
      a[2] = (short)f2bf(xa.z); a[3] = (short)f2bf(xa.w);
      a[4] = (short)f2bf(xc.x); a[5] = (short)f2bf(xc.y);
      a[6] = (short)f2bf(xc.z); a[7] = (short)f2bf(xc.w);
#pragma unroll
      for (int cb = 0; cb < 8; ++cb) {
        bf16x8 bb = *(const bf16x8*)(wtb + (size_t)(cb * 16 + r) * 128 + wo);
        accB[cb] = __builtin_amdgcn_mfma_f32_16x16x32_bf16(a, bb, accB[cb], 0, 0, 0);
        bf16x8 bs = *(const bf16x8*)(wts + (size_t)(cb * 16 + r) * 128 + wo);
        accS[cb] = __builtin_amdgcn_mfma_f32_16x16x32_bf16(a, bs, accS[cb], 0, 0, 0);
      }
    }
    // reduce dots across kg groups (lanes r, r+16, r+32, r+48)
    p0 += __shfl_xor(p0, 16); p0 += __shfl_xor(p0, 32);
    p1 += __shfl_xor(p1, 16); p1 += __shfl_xor(p1, 32);
    p2 += __shfl_xor(p2, 16); p2 += __shfl_xor(p2, 32);
    p3 += __shfl_xor(p3, 16); p3 += __shfl_xor(p3, 32);
    if (lane < 16) {
      int row = m0 + lane;
      ssb[row] = p0; sdb[row] = p1; sss[row] = p2; sds[row] = p3;
    }
#pragma unroll
    for (int cb = 0; cb < 4; ++cb)
#pragma unroll
      for (int i = 0; i < 4; ++i) {
        size_t idx = (size_t)(m0 + kg * 4 + i) * 64 + cb * 16 + r;
        hbp[idx] = (unsigned int)f2bf(accB[cb][i]) | ((unsigned int)f2bf(accB[cb + 4][i]) << 16);
        hsp[idx] = (unsigned int)f2bf(accS[cb][i]) | ((unsigned int)f2bf(accS[cb + 4][i]) << 16);
      }
  } else if (blk < GEMM_BLKS + ENC_BLKS) {
    // ---- edge encode -> alpha_e ----
    int idx = (blk - GEMM_BLKS) * 256 + t;
    const float* encW = consts + 544;
    bool isB = idx < Bc * EB;
    const float* attr = isB ? battr : sattr;
    const float* wae = consts + (isB ? 2 : 6);
    float* dst = isB ? aeb : aes;
    int id2 = isB ? idx : idx - Bc * EB;
    float4 at = *(const float4*)(attr + (size_t)id2 * 4);
    float e0 = encW[16] + at.x * encW[0] + at.y * encW[4] + at.z * encW[8]  + at.w * encW[12];
    float e1 = encW[17] + at.x * encW[1] + at.y * encW[5] + at.z * encW[9]  + at.w * encW[13];
    float e2 = encW[18] + at.x * encW[2] + at.y * encW[6] + at.z * encW[10] + at.w * encW[14];
    float e3 = encW[19] + at.x * encW[3] + at.y * encW[7] + at.z * encW[11] + at.w * encW[15];
    dst[id2] = e0 * wae[0] + e1 * wae[1] + e2 * wae[2] + e3 * wae[3];
  } else {
    // ---- ELL scatter (src<<16 | edge); fill counters zeroed by k_setup ----
    int tid = (blk - GEMM_BLKS - ENC_BLKS) * 256 + t;
    if (tid < EB) {
      int d = bdst[tid];
      int slot = atomicAdd(&filb[d], 1);
      if (slot < CAP) ellb[(size_t)d * CAP + slot] = ((unsigned int)bsrc[tid] << 16) | (unsigned int)tid;
    } else if (tid < EB + ES) {
      int e = tid - EB;
      int d = sdst[e];
      int slot = atomicAdd(&fils[d], 1);
      if (slot < CAP) ells[(size_t)d * CAP + slot] = ((unsigned int)ssrcA[e] << 16) | (unsigned int)e;
    }
  }
}

// ---- fused gather: ELL softmax (no-max) + 8-deep batched accumulate ----
__global__ __launch_bounds__(256) void k_gather(
    const float* ssb, const float* sdb, const float* aeb,
    const int* filb, const unsigned int* ellb, const unsigned int* hbp, const float* bias_b,
    const float* sss, const float* sds, const float* aes,
    const int* fils, const unsigned int* ells, const unsigned int* hsp, const float* bias_s,
    const float* consts, float* out) {
  __shared__ uint4 lds[4][128];   // [wave][0..63]=bend slots, [64..127]=sec slots
  int wg = blockIdx.x;
  int wave = threadIdx.x >> 6, lane = threadIdx.x & 63;
  int b = wg & 7;
  int i = ((wg >> 3) << 2) + wave;        // node in batch [0,4096)
  int wid = (b << 12) + i;
  int il = i & 255;
  int rowBase = wid - il;

  float oB0 = 0.f, oB1 = 0.f, oS0 = 0.f, oS1 = 0.f;

  int degB = filb[i];  if (degB > CAP) degB = CAP;
  int degS = fils[il]; if (degS > CAP) degS = CAP;
  const float* ssrcBb = ssb + ((size_t)b << 12);
  const float* ssrcGs = sss + rowBase;
  const float* aeBb = aeb + (size_t)b * EB;
  const float* aeBs = aes + (size_t)b * ES;
  const unsigned int* hBb = hbp + (((size_t)b << 12) << 6);
  const unsigned int* hGs = hsp + ((size_t)rowBase << 6);
  const unsigned int* ellBr = ellb + (size_t)i * CAP;
  const unsigned int* ellSr = ells + (size_t)il * CAP;
  unsigned int uSelfB = hbp[((size_t)wid << 6) + lane];
  unsigned int uSelfS = hsp[((size_t)wid << 6) + lane];
  float sdB = sdb[wid], sdS = sds[wid];
  float ssSelfB = ssrcBb[i], ssSelfS = ssrcGs[il];

  uint4* ldsw = lds[wave];

  if (degB <= 64 && degS <= 64) {
    bool vB = lane < degB, vS = lane < degS;
    unsigned int evB = vB ? ellBr[lane] : 0u;
    unsigned int evS = vS ? ellSr[lane] : 0u;
    int sB = evB >> 16, sS = evS >> 16;
    int eB = evB & 0xffffu, eS = evS & 0xffffu;
    float aevB = vB ? aeBb[eB] : 0.f;
    float aevS = vS ? aeBs[eS] : 0.f;
    float xsB = ssrcBb[sB];
    float xsS = ssrcGs[sS];

    // exp without max-subtraction: scores |a| <~ 15, f32 exp safe to ~88
    float cB = vB ? __expf(lrelu(xsB + sdB + aevB, NEG_ATT)) : 0.f;
    float cS2 = vS ? __expf(lrelu(xsS + sdS + aevS, NEG_ATT)) : 0.f;

    float asumB = aevB, asumS = aevS, seB = cB, seS = cS2;
    for (int off = 32; off; off >>= 1) {
      asumB += __shfl_xor(asumB, off);
      asumS += __shfl_xor(asumS, off);
      seB += __shfl_xor(seB, off);
      seS += __shfl_xor(seS, off);
    }
    float aSB = lrelu(ssSelfB + sdB + asumB / (float)(degB > 0 ? degB : 1), NEG_ATT);
    float aSS = lrelu(ssSelfS + sdS + asumS / (float)(degS > 0 ? degS : 1), NEG_ATT);
    float eSB = __expf(aSB), eSS = __expf(aSS);
    float invB = 1.f / (seB + eSB);
    float invS = 1.f / (seS + eSS);

    // publish slots: (byteoff, cpk_lo, cpk_hi, f32 c)
    {
      float cnB = cB * invB, cnS = cS2 * invS;
      unsigned int cb16 = (unsigned int)f2bf(cnB);
      unsigned int cs16 = (unsigned int)f2bf(cnS);
      uint4 slotB, slotS;
      slotB.x = (unsigned int)sB << 8; slotB.y = cb16; slotB.z = cb16 << 16; slotB.w = __float_as_uint(cnB);
      slotS.x = (unsigned int)sS << 8; slotS.y = cs16; slotS.z = cs16 << 16; slotS.w = __float_as_uint(cnS);
      ldsw[lane] = slotB;
      ldsw[64 + lane] = slotS;
    }

    const char* hBc = (const char*)hBb;
    const char* hGc = (const char*)hGs;
    int lb4 = lane * 4;
    int j = 0;
    for (; j + 8 <= degB; j += 8) {       // 8 loads in flight
      uint4 v0 = ldsw[j],   v1 = ldsw[j+1], v2 = ldsw[j+2], v3 = ldsw[j+3];
      uint4 v4 = ldsw[j+4], v5 = ldsw[j+5], v6 = ldsw[j+6], v7 = ldsw[j+7];
      unsigned int u0 = *(const unsigned int*)(hBc + v0.x + lb4);
      unsigned int u1 = *(const unsigned int*)(hBc + v1.x + lb4);
      unsigned int u2 = *(const unsigned int*)(hBc + v2.x + lb4);
      unsigned int u3 = *(const unsigned int*)(hBc + v3.x + lb4);
      unsigned int u4 = *(const unsigned int*)(hBc + v4.x + lb4);
      unsigned int u5 = *(const unsigned int*)(hBc + v5.x + lb4);
      unsigned int u6 = *(const unsigned int*)(hBc + v6.x + lb4);
      unsigned int u7 = *(const unsigned int*)(hBc + v7.x + lb4);
      edge_fma(u0, v0, oB0, oB1); edge_fma(u1, v1, oB0, oB1);
      edge_fma(u2, v2, oB0, oB1); edge_fma(u3, v3, oB0, oB1);
      edge_fma(u4, v4, oB0, oB1); edge_fma(u5, v5, oB0, oB1);
      edge_fma(u6, v6, oB0, oB1); edge_fma(u7, v7, oB0, oB1);
    }
    for (; j + 4 <= degB; j += 4) {
      uint4 v0 = ldsw[j], v1 = ldsw[j+1], v2 = ldsw[j+2], v3 = ldsw[j+3];
      unsigned int u0 = *(const unsigned int*)(hBc + v0.x + lb4);
      unsigned int u1 = *(const unsigned int*)(hBc + v1.x + lb4);
      unsigned int u2 = *(const unsigned int*)(hBc + v2.x + lb4);
      unsigned int u3 = *(const unsigned int*)(hBc + v3.x + lb4);
      edge_fma(u0, v0, oB0, oB1); edge_fma(u1, v1, oB0, oB1);
      edge_fma(u2, v2, oB0, oB1); edge_fma(u3, v3, oB0, oB1);
    }
    for (; j < degB; ++j) {
      uint4 v = ldsw[j];
      unsigned int u = *(const unsigned int*)(hBc + v.x + lb4);
      edge_fma(u, v, oB0, oB1);
    }
    j = 0;
    for (; j + 8 <= degS; j += 8) {
      uint4 v0 = ldsw[64+j],   v1 = ldsw[64+j+1], v2 = ldsw[64+j+2], v3 = ldsw[64+j+3];
      uint4 v4 = ldsw[64+j+4], v5 = ldsw[64+j+5], v6 = ldsw[64+j+6], v7 = ldsw[64+j+7];
      unsigned int u0 = *(const unsigned int*)(hGc + v0.x + lb4);
      unsigned int u1 = *(const unsigned int*)(hGc + v1.x + lb4);
      unsigned int u2 = *(const unsigned int*)(hGc + v2.x + lb4);
      unsigned int u3 = *(const unsigned int*)(hGc + v3.x + lb4);
      unsigned int u4 = *(const unsigned int*)(hGc + v4.x + lb4);
      unsigned int u5 = *(const unsigned int*)(hGc + v5.x + lb4);
      unsigned int u6 = *(const unsigned int*)(hGc + v6.x + lb4);
      unsigned int u7 = *(const unsigned int*)(hGc + v7.x + lb4);
      edge_fma(u0, v0, oS0, oS1); edge_fma(u1, v1, oS0, oS1);
      edge_fma(u2, v2, oS0, oS1); edge_fma(u3, v3, oS0, oS1);
      edge_fma(u4, v4, oS0, oS1); edge_fma(u5, v5, oS0, oS1);
      edge_fma(u6, v6, oS0, oS1); edge_fma(u7, v7, oS0, oS1);
    }
    for (; j + 4 <= degS; j += 4) {
      uint4 v0 = ldsw[64+j], v1 = ldsw[64+j+1], v2 = ldsw[64+j+2], v3 = ldsw[64+j+3];
      unsigned int u0 = *(const unsigned int*)(hGc + v0.x + lb4);
      unsigned int u1 = *(const unsigned int*)(hGc + v1.x + lb4);
      unsigned int u2 = *(const unsigned int*)(hGc + v2.x + lb4);
      unsigned int u3 = *(const unsigned int*)(hGc + v3.x + lb4);
      edge_fma(u0, v0, oS0, oS1); edge_fma(u1, v1, oS0, oS1);
      edge_fma(u2, v2, oS0, oS1); edge_fma(u3, v3, oS0, oS1);
    }
    for (; j < degS; ++j) {
      uint4 v = ldsw[64+j];
      unsigned int u = *(const unsigned int*)(hGc + v.x + lb4);
      edge_fma(u, v, oS0, oS1);
    }
    // self-loop terms
    float cSelfB = eSB * invB;
    oB0 += cSelfB * bflo(uSelfB); oB1 += cSelfB * bfhi(uSelfB);
    float cSelfS = eSS * invS;
    oS0 += cSelfS * bflo(uSelfS); oS1 += cSelfS * bfhi(uSelfS);
  } else {
    // ---- cold fallback (64 < deg <= CAP), strided 3-pass + serial accumulate ----
    float mB, invB, aSB, mS, invS, aSS;
    {
      float asum = 0.f;
      for (int p = lane; p < degB; p += 64) asum += aeBb[ellBr[p] & 0xffffu];
      for (int off = 32; off; off >>= 1) asum += __shfl_xor(asum, off);
      aSB = lrelu(ssSelfB + sdB + asum / (float)(degB > 0 ? degB : 1), NEG_ATT);
      mB = aSB;
      for (int p = lane; p < degB; p += 64) {
        unsigned int v = ellBr[p];
        mB = fmaxf(mB, lrelu(ssrcBb[v >> 16] + sdB + aeBb[v & 0xffffu], NEG_ATT));
      }
      for (int off = 32; off; off >>= 1) mB = fmaxf(mB, __shfl_xor(mB, off));
      float se = 0.f;
      for (int p = lane; p < degB; p += 64) {
        unsigned int v = ellBr[p];
        se += __expf(lrelu(ssrcBb[v >> 16] + sdB + aeBb[v & 0xffffu], NEG_ATT) - mB);
      }
      for (int off = 32; off; off >>= 1) se += __shfl_xor(se, off);
      se += __expf(aSB - mB);
      invB = 1.f / se;
      for (int j = 0; j < degB; ++j) {
        unsigned int v = ellBr[j];
        int s = v >> 16;
        float c = __expf(lrelu(ssrcBb[s] + sdB + aeBb[v & 0xffffu], NEG_ATT) - mB) * invB;
        unsigned int u = (hBb + ((size_t)s << 6))[lane];
        oB0 += c * bflo(u); oB1 += c * bfhi(u);
      }
      float cSelfB = __expf(aSB - mB) * invB;
      oB0 += cSelfB * bflo(uSelfB); oB1 += cSelfB * bfhi(uSelfB);
    }
    {
      float asum = 0.f;
      for (int p = lane; p < degS; p += 64) asum += aeBs[ellSr[p] & 0xffffu];
      for (int off = 32; off; off >>= 1) asum += __shfl_xor(asum, off);
      aSS = lrelu(ssSelfS + sdS + asum / (float)(degS > 0 ? degS : 1), NEG_ATT);
      mS = aSS;
      for (int p = lane; p < degS; p += 64) {
        unsigned int v = ellSr[p];
        mS = fmaxf(mS, lrelu(ssrcGs[v >> 16] + sdS + aeBs[v & 0xffffu], NEG_ATT));
      }
      for (int off = 32; off; off >>= 1) mS = fmaxf(mS, __shfl_xor(mS, off));
      float se = 0.f;
      for (int p = lane; p < degS; p += 64) {
        unsigned int v = ellSr[p];
        se += __expf(lrelu(ssrcGs[v >> 16] + sdS + aeBs[v & 0xffffu], NEG_ATT) - mS);
      }
      for (int off = 32; off; off >>= 1) se += __shfl_xor(se, off);
      se += __expf(aSS - mS);
      invS = 1.f / se;
      for (int j = 0; j < degS; ++j) {
        unsigned int v = ellSr[j];
        int s = v >> 16;
        float c = __expf(lrelu(ssrcGs[s] + sdS + aeBs[v & 0xffffu], NEG_ATT) - mS) * invS;
        unsigned int u = (hGs + ((size_t)s << 6))[lane];
        oS0 += c * bflo(u); oS1 += c * bfhi(u);
      }
      float cSelfS = __expf(aSS - mS) * invS;
      oS0 += cSelfS * bflo(uSelfS); oS1 += cSelfS * bfhi(uSelfS);
    }
  }

  float w0 = consts[0], w1 = consts[1];
  size_t o = (size_t)wid << 7;
  out[o + lane]      = w0 * lrelu(oB0 + bias_b[lane], NEG_OUT)      + w1 * (oS0 + bias_s[lane]);
  out[o + 64 + lane] = w0 * lrelu(oB1 + bias_b[lane + 64], NEG_OUT) + w1 * (oS1 + bias_s[lane + 64]);
}

extern "C" void kernel_launch(void* const* d_in, const int* in_sizes, int n_in,
                              void* d_out, int out_size, void* d_ws, size_t ws_size,
                              hipStream_t stream) {
  (void)in_sizes; (void)n_in; (void)out_size; (void)ws_size;
  const float* x        = (const float*)d_in[0];
  const int*   sec_ei   = (const int*)d_in[1];
  const int*   bend_ei  = (const int*)d_in[2];
  const float* sec_attr = (const float*)d_in[3];
  const float* bend_attr= (const float*)d_in[4];
  const float* enc_W    = (const float*)d_in[5];
  const float* enc_b    = (const float*)d_in[6];
  const float* Wb       = (const float*)d_in[7];
  const float* a_src_b  = (const float*)d_in[8];
  const float* a_dst_b  = (const float*)d_in[9];
  const float* We_b     = (const float*)d_in[10];
  const float* a_edge_b = (const float*)d_in[11];
  const float* bias_b   = (const float*)d_in[12];
  const float* Ws       = (const float*)d_in[13];
  const float* a_src_s  = (const float*)d_in[14];
  const float* a_dst_s  = (const float*)d_in[15];
  const float* We_s     = (const float*)d_in[16];
  const float* a_edge_s = (const float*)d_in[17];
  const float* bias_s   = (const float*)d_in[18];
  const float* fuse_w   = (const float*)d_in[19];
  float* out = (float*)d_out;

  char* ws = (char*)d_ws;
  float* consts = (float*)(ws + OFF_CONSTS);
  unsigned short* wtb = (unsigned short*)(ws + OFF_WTB);
  unsigned short* wts = (unsigned short*)(ws + OFF_WTS);
  unsigned int* hbp = (unsigned int*)(ws + OFF_HBP);
  unsigned int* hsp = (unsigned int*)(ws + OFF_HSP);
  float* ssb = (float*)(ws + OFF_SSB);
  float* sdb = (float*)(ws + OFF_SDB);
  float* sss = (float*)(ws + OFF_SSS);
  float* sds = (float*)(ws + OFF_SDS);
  float* aeb = (float*)(ws + OFF_AEB);
  float* aes = (float*)(ws + OFF_AES);
  unsigned int* ellb = (unsigned int*)(ws + OFF_ELLB);
  unsigned int* ells = (unsigned int*)(ws + OFF_ELLS);
  int* filb = (int*)(ws + OFF_FILB);
  int* fils = (int*)(ws + OFF_FILS);
  unsigned int* fill_region = (unsigned int*)(ws + OFF_FILB);

  const int* bend_src = bend_ei;
  const int* bend_dst = bend_ei + EB;
  const int* sec_src  = sec_ei;
  const int* sec_dst  = sec_ei + ES;

  k_setup<<<164, 256, 0, stream>>>(Wb, a_src_b, a_dst_b, Ws, a_src_s, a_dst_s,
                                   We_b, a_edge_b, We_s, a_edge_s, fuse_w,
                                   enc_W, enc_b, consts, wtb, wts, fill_region);

  k_work<<<GEMM_BLKS + ENC_BLKS + SCAT_BLKS, 256, 0, stream>>>(
      x, consts, wtb, wts, hbp, hsp, ssb, sdb, sss, sds,
      bend_attr, sec_attr, aeb, aes,
      bend_src, bend_dst, sec_src, sec_dst,
      filb, fils, ellb, ells);

  k_gather<<<NROWS / 4, 256, 0, stream>>>(ssb, sdb, aeb, filb, ellb, hbp, bias_b,
                                          sss, sds, aes, fils, ells, hsp, bias_s,
                                          consts, out);
}